// Round 1
// baseline (9179.379 us; speedup 1.0000x reference)
//
#include <hip/hip_runtime.h>
#include <cstdint>
#include <cstddef>

// ---------------------------------------------------------------------------
// 5-layer stacked LSTM (B=4096, T=256, H=50, D_in=1) + final FC, fp32.
//
// Decomposition: 256 blocks x 16 batch rows. Rows are independent across the
// whole network -> each block runs all 5 layers x 256 timesteps privately.
// No inter-block communication, no grid sync.
//
// Per layer: weights transposed into LDS as [i][us][WPAD=20] so each thread's
// 13 gate-weights are read as 3x ds_read_b128 + 1x b32 (20-word stride =
// 80 B => 16B-aligned, bank-group stride 5 mod 8 => <=2-way conflicts = free).
// h,c live in LDS; inter-layer sequence goes through d_ws in place
// (ys[block][t][row][h], 209,715,200 bytes required).
// ---------------------------------------------------------------------------

#define HSZ   50
#define G4    200           // 4*H
#define TSEQ  256
#define BATCH 4096
#define BS    16            // batch rows per block
#define NBLK  (BATCH / BS)  // 256
#define NTHR  256
#define NUS   16            // gate slices per row
#define GPT   13            // gates per slice (16*13 = 208 >= 200)
#define WPAD  20            // padded words per slice
#define ROWL  (BS * HSZ)    // 800

__device__ __forceinline__ float sigf(float x) {
  return __builtin_amdgcn_rcpf(1.0f + __expf(-x));
}
__device__ __forceinline__ float tanh_f(float x) {
  // tanh(x) = 2*sigmoid(2x) - 1
  return fmaf(2.0f, __builtin_amdgcn_rcpf(1.0f + __expf(-2.0f * x)), -1.0f);
}

// exact floor divides for small ranges (verified: idx<10000 for /50, u<208 for /13)
__device__ __forceinline__ int div50(int v) { return (int)(((unsigned)v * 5243u) >> 18); }
__device__ __forceinline__ int div13(int v) { return (int)(((unsigned)v * 5042u) >> 16); }

// 13 fmas of one input value against this thread's weight slice (b128 loads)
#define GATE13(WBASE, XV) do {                                            \
  const float* _wp = (WBASE);                                             \
  float4 _w0 = *(const float4*)(_wp);                                     \
  float4 _w1 = *(const float4*)(_wp + 4);                                 \
  float4 _w2 = *(const float4*)(_wp + 8);                                 \
  float  _wc = _wp[12];                                                   \
  acc[0]  = fmaf(_w0.x, (XV), acc[0]);  acc[1]  = fmaf(_w0.y, (XV), acc[1]);  \
  acc[2]  = fmaf(_w0.z, (XV), acc[2]);  acc[3]  = fmaf(_w0.w, (XV), acc[3]);  \
  acc[4]  = fmaf(_w1.x, (XV), acc[4]);  acc[5]  = fmaf(_w1.y, (XV), acc[5]);  \
  acc[6]  = fmaf(_w1.z, (XV), acc[6]);  acc[7]  = fmaf(_w1.w, (XV), acc[7]);  \
  acc[8]  = fmaf(_w2.x, (XV), acc[8]);  acc[9]  = fmaf(_w2.y, (XV), acc[9]);  \
  acc[10] = fmaf(_w2.z, (XV), acc[10]); acc[11] = fmaf(_w2.w, (XV), acc[11]); \
  acc[12] = fmaf(_wc,   (XV), acc[12]);                                   \
} while (0)

__global__ void __launch_bounds__(NTHR, 1)
lstm5_kernel(const float* __restrict__ x,
             const float* __restrict__ w_ih0, const float* __restrict__ w_hh0,
             const float* __restrict__ b0,
             const float* __restrict__ w_ih,  const float* __restrict__ w_hh,
             const float* __restrict__ b,
             const float* __restrict__ fc_w,  const float* __restrict__ fc_b,
             float* __restrict__ out, float* __restrict__ ys)
{
  // LDS: 64000 + 64000 + 1280 + 3*3200 + 12800 = 151,680 B  (< 160 KiB)
  __shared__ __align__(16) float s_wih[HSZ * NUS * WPAD];
  __shared__ __align__(16) float s_whh[HSZ * NUS * WPAD];
  __shared__ __align__(16) float s_bias[NUS * WPAD];
  __shared__ __align__(16) float s_x[ROWL];
  __shared__ __align__(16) float s_h[ROWL];
  __shared__ __align__(16) float s_c[ROWL];
  __shared__ __align__(16) float s_g[BS * G4];

  const int tid = threadIdx.x;
  const int blk = blockIdx.x;
  const int us  = tid & 15;   // gate-slice index: owns gates [us*13, us*13+13)
  const int rr  = tid >> 4;   // local batch row 0..15
  float* __restrict__ ysb = ys + (size_t)blk * (TSEQ * ROWL);

  for (int layer = 0; layer < 5; ++layer) {
    // ---------------- stage this layer's weights into LDS ----------------
    for (int i = tid; i < HSZ * NUS * WPAD; i += NTHR) { s_wih[i] = 0.0f; s_whh[i] = 0.0f; }
    if (tid < NUS * WPAD) s_bias[tid] = 0.0f;
    __syncthreads();

    const float* whh_src = (layer == 0) ? w_hh0 : (w_hh + (size_t)(layer - 1) * G4 * HSZ);
    const float* b_src   = (layer == 0) ? b0    : (b    + (size_t)(layer - 1) * G4);
    for (int idx = tid; idx < G4 * HSZ; idx += NTHR) {   // src is [u][i] row-major
      int u = div50(idx), i = idx - u * 50;
      int uu = div13(u),  j = u - uu * 13;
      s_whh[(i * NUS + uu) * WPAD + j] = whh_src[idx];
    }
    if (layer == 0) {
      if (tid < G4) {                                     // w_ih0 is [200,1]
        int uu = div13(tid), j = tid - uu * 13;
        s_wih[uu * WPAD + j] = w_ih0[tid];                // i = 0 slice
      }
    } else {
      const float* wih_src = w_ih + (size_t)(layer - 1) * G4 * HSZ;
      for (int idx = tid; idx < G4 * HSZ; idx += NTHR) {
        int u = div50(idx), i = idx - u * 50;
        int uu = div13(u),  j = u - uu * 13;
        s_wih[(i * NUS + uu) * WPAD + j] = wih_src[idx];
      }
    }
    if (tid < G4) {
      int uu = div13(tid), j = tid - uu * 13;
      s_bias[uu * WPAD + j] = b_src[tid];
    }
    // zero h, c;  load x_0
    for (int idx = tid; idx < ROWL; idx += NTHR) { s_h[idx] = 0.0f; s_c[idx] = 0.0f; }
    if (layer == 0) {
      if (tid < BS) s_x[tid] = x[(size_t)(blk * BS + tid) * TSEQ];
    } else {
      for (int idx = tid; idx < ROWL; idx += NTHR) s_x[idx] = ysb[idx];
    }
    __syncthreads();

    // ---------------------------- time loop ------------------------------
    for (int t = 0; t < TSEQ; ++t) {
      // prefetch x_{t+1} into registers (hidden under the gate GEMM)
      const int nt = (t + 1 < TSEQ) ? (t + 1) : t;
      float xn0 = 0.0f, xn1 = 0.0f, xn2 = 0.0f, xn3 = 0.0f;
      if (layer == 0) {
        if (tid < BS) xn0 = x[(size_t)(blk * BS + tid) * TSEQ + nt];
      } else {
        xn0 = ysb[nt * ROWL + tid];
        xn1 = ysb[nt * ROWL + tid + 256];
        xn2 = ysb[nt * ROWL + tid + 512];
        if (tid < ROWL - 768) xn3 = ysb[nt * ROWL + tid + 768];
      }

      // ---- gate pre-activations: acc = bias + W_ih x_t + W_hh h_{t-1} ----
      float acc[GPT];
      {
        const float* bp = s_bias + us * WPAD;
        float4 b0v = *(const float4*)(bp);
        float4 b1v = *(const float4*)(bp + 4);
        float4 b2v = *(const float4*)(bp + 8);
        acc[0] = b0v.x; acc[1] = b0v.y; acc[2]  = b0v.z; acc[3]  = b0v.w;
        acc[4] = b1v.x; acc[5] = b1v.y; acc[6]  = b1v.z; acc[7]  = b1v.w;
        acc[8] = b2v.x; acc[9] = b2v.y; acc[10] = b2v.z; acc[11] = b2v.w;
        acc[12] = bp[12];
      }
      if (layer == 0) {
        float xv = s_x[rr];
        GATE13(s_wih + us * WPAD, xv);
      } else {
        const float* xr = s_x + rr * HSZ;
        #pragma unroll 5
        for (int i = 0; i < HSZ; ++i) {
          GATE13(s_wih + (i * NUS + us) * WPAD, xr[i]);
        }
      }
      {
        const float* hr = s_h + rr * HSZ;
        #pragma unroll 5
        for (int i = 0; i < HSZ; ++i) {
          GATE13(s_whh + (i * NUS + us) * WPAD, hr[i]);
        }
      }
      { // write raw gates (mask the 8 pad gates of slice 15)
        float* gp = s_g + rr * G4 + us * GPT;
        const int ub = us * GPT;
        #pragma unroll
        for (int j = 0; j < GPT; ++j) if (ub + j < G4) gp[j] = acc[j];
      }
      __syncthreads();   // gates visible; s_x now dead -> safe to overwrite

      // stash prefetched x_{t+1}
      if (layer == 0) {
        if (tid < BS) s_x[tid] = xn0;
      } else {
        s_x[tid] = xn0; s_x[tid + 256] = xn1; s_x[tid + 512] = xn2;
        if (tid < ROWL - 768) s_x[tid + 768] = xn3;
      }
      // ---- pointwise cell update (same idx partition as the stores) ----
      #pragma unroll
      for (int m = 0; m < 4; ++m) {
        int idx = tid + 256 * m;
        if (idx < ROWL) {
          int r = div50(idx), k = idx - r * 50;
          const float* gr = s_g + r * G4 + k;
          float ig = sigf(gr[0]);
          float fg = sigf(gr[50]);
          float gg = tanh_f(gr[100]);
          float og = sigf(gr[150]);
          float cv = fmaf(fg, s_c[idx], ig * gg);
          s_c[idx] = cv;
          float hv = og * tanh_f(cv);
          s_h[idx] = hv;
          if (layer < 4) ysb[t * ROWL + idx] = hv;   // in-place layer output
        }
      }
      __syncthreads();   // h_t and x_{t+1} visible for next step
    }
  }

  // ------------------------------ FC head --------------------------------
  if (tid < BS) {
    float a = fc_b[0];
    const float* hr = s_h + tid * HSZ;
    #pragma unroll
    for (int i = 0; i < HSZ; ++i) a = fmaf(hr[i], fc_w[i], a);
    out[blk * BS + tid] = a;
  }
}

extern "C" void kernel_launch(void* const* d_in, const int* in_sizes, int n_in,
                              void* d_out, int out_size, void* d_ws, size_t ws_size,
                              hipStream_t stream) {
  (void)in_sizes; (void)n_in; (void)out_size; (void)ws_size;
  const float* x     = (const float*)d_in[0];
  const float* w_ih0 = (const float*)d_in[1];
  const float* w_hh0 = (const float*)d_in[2];
  const float* b0    = (const float*)d_in[3];
  const float* w_ih  = (const float*)d_in[4];
  const float* w_hh  = (const float*)d_in[5];
  const float* b     = (const float*)d_in[6];
  const float* fc_w  = (const float*)d_in[7];
  const float* fc_b  = (const float*)d_in[8];
  float* out = (float*)d_out;
  float* ys  = (float*)d_ws;   // needs 4096*256*50*4 = 209,715,200 B of d_ws

  hipLaunchKernelGGL(lstm5_kernel, dim3(NBLK), dim3(NTHR), 0, stream,
                     x, w_ih0, w_hh0, b0, w_ih, w_hh, b, fc_w, fc_b, out, ys);
}